// Round 5
// baseline (804.763 us; speedup 1.0000x reference)
//
#include <hip/hip_runtime.h>
#include <hip/hip_bf16.h>

typedef __attribute__((ext_vector_type(8))) short bf16x8_t;
typedef __attribute__((ext_vector_type(4))) float f32x4_t;

__device__ __forceinline__ unsigned bfr(float x) {
  unsigned u = __builtin_bit_cast(unsigned, x);
  return (u + 0x7fffu + ((u >> 16) & 1u)) >> 16;
}
__device__ __forceinline__ unsigned pk2(float lo, float hi) {
  return bfr(lo) | (bfr(hi) << 16);
}

// ---------------------------------------------------------------------------
// Conv 3x3 stride2 pad1 + bias + relu + per-channel sum/sumsq stats.
// Block = (BPB batches, OHS output rows). Each thread owns ONE output pixel
// and computes ALL 24 output channels. BN of the input applied at stage time.
// ---------------------------------------------------------------------------
template<int CIN, int H, int OHS, int BPB, bool BNIN>
__global__ __launch_bounds__(256) void convk(
    const float* __restrict__ x, const float* __restrict__ wgt,
    const float* __restrict__ bias,
    const float* __restrict__ instats,
    const float* __restrict__ ing, const float* __restrict__ inb,
    float* __restrict__ y, float* __restrict__ stats)
{
  constexpr int W = H, HO = H / 2, WO = W / 2;
  constexpr int NR = 2 * OHS + 1;
  constexpr int TW = W + 1;
  constexpr int SPB = HO / OHS;
  constexpr int NSTG = BPB * NR * W;

  __shared__ float tile[2][BPB][NR][TW];
  __shared__ float scb[CIN], shb[CIN];
  __shared__ float sred[24], sqd[24];

  const int tid = threadIdx.x;
  const int b0 = (blockIdx.x / SPB) * BPB;
  const int strip = blockIdx.x % SPB;
  const int oh0 = strip * OHS;

  if (BNIN && tid < CIN) {
    const float cnt = 64.f * H * W;
    const float m = instats[tid] / cnt;
    const float v = instats[24 + tid] / cnt - m * m;
    const float s = rsqrtf(v + 1e-5f) * ing[tid];
    scb[tid] = s;
    shb[tid] = inb[tid] - m * s;
  }
  if (tid < 24) { sred[tid] = 0.f; sqd[tid] = 0.f; }
  for (int i = tid; i < 2 * BPB * NR; i += 256) {
    const int bufi = i / (BPB * NR), rem = i % (BPB * NR);
    tile[bufi][rem / NR][rem % NR][0] = 0.f;
  }
  __syncthreads();

  const int ow  = tid % WO;
  const int ohl = (tid / WO) % OHS;
  const int bs  = tid / (WO * OHS);
  const int oh  = oh0 + ohl;

  float acc[24];
  #pragma unroll
  for (int co = 0; co < 24; ++co) acc[co] = bias[co];

  {
    const float sc = BNIN ? scb[0] : 1.f, sh = BNIN ? shb[0] : 0.f;
    for (int idx = tid; idx < NSTG; idx += 256) {
      const int c = idx % W, rr = idx / W;
      const int rl = rr % NR, sb = rr / NR;
      const int ih = oh0 * 2 - 1 + rl;
      float v = 0.f;
      if (ih >= 0)
        v = x[((size_t)((b0 + sb) * CIN + 0) * H + ih) * W + c] * sc + sh;
      tile[0][sb][rl][c + 1] = v;
    }
  }
  __syncthreads();

  for (int ci = 0; ci < CIN; ++ci) {
    if (ci + 1 < CIN) {
      const float sc = BNIN ? scb[ci + 1] : 1.f, sh = BNIN ? shb[ci + 1] : 0.f;
      for (int idx = tid; idx < NSTG; idx += 256) {
        const int c = idx % W, rr = idx / W;
        const int rl = rr % NR, sb = rr / NR;
        const int ih = oh0 * 2 - 1 + rl;
        float v = 0.f;
        if (ih >= 0)
          v = x[((size_t)((b0 + sb) * CIN + ci + 1) * H + ih) * W + c] * sc + sh;
        tile[(ci + 1) & 1][sb][rl][c + 1] = v;
      }
    }
    float tp[9];
    #pragma unroll
    for (int r = 0; r < 3; ++r)
      #pragma unroll
      for (int s = 0; s < 3; ++s)
        tp[r * 3 + s] = tile[ci & 1][bs][2 * ohl + r][2 * ow + s];
    #pragma unroll
    for (int co = 0; co < 24; ++co) {
      const float* wp = wgt + (size_t)(co * CIN + ci) * 9;
      float a = acc[co];
      #pragma unroll
      for (int k = 0; k < 9; ++k) a += tp[k] * wp[k];
      acc[co] = a;
    }
    __syncthreads();
  }

  const int lane = tid & 63;
  #pragma unroll
  for (int co = 0; co < 24; ++co) {
    const float v = fmaxf(acc[co], 0.f);
    acc[co] = v;
    y[((size_t)((b0 + bs) * 24 + co) * HO + oh) * WO + ow] = v;
  }
  #pragma unroll
  for (int co = 0; co < 24; ++co) {
    float v = acc[co], q = v * v;
    #pragma unroll
    for (int d = 1; d < 64; d <<= 1) {
      v += __shfl_xor(v, d, 64);
      q += __shfl_xor(q, d, 64);
    }
    if (lane == 0) {
      atomicAdd(&sred[co], v);
      atomicAdd(&sqd[co], q);
    }
  }
  __syncthreads();
  if (tid < 24) {
    atomicAdd(&stats[tid], sred[tid]);
    atomicAdd(&stats[24 + tid], sqd[tid]);
  }
}

// ---------------------------------------------------------------------------
// Build A = o @ Wi, B = o @ Wj (BN of x4 fused), plus Cq (blocks with p==0).
// ---------------------------------------------------------------------------
__global__ __launch_bounds__(256) void build_ab(
    const float* __restrict__ x4, const float* __restrict__ stats4,
    const float* __restrict__ g4, const float* __restrict__ b4,
    const float* __restrict__ gw1, const float* __restrict__ gb1,
    const float* __restrict__ qst,
    float* __restrict__ A, float* __restrict__ Bm, float* __restrict__ Cq)
{
  const int bp = blockIdx.x;
  const int b = bp >> 6, p = bp & 63;
  const int t = threadIdx.x;
  __shared__ float o[26];
  if (t < 24) {
    const float m = stats4[t] * (1.f / 4096.f);
    const float v = stats4[24 + t] * (1.f / 4096.f) - m * m;
    const float sc = rsqrtf(v + 1e-5f) * g4[t];
    const float sh = b4[t] - m * sc;
    o[t] = x4[(size_t)(b * 24 + t) * 64 + p] * sc + sh;
  } else if (t == 24) o[24] = (float)(p >> 3);
  else if (t == 25) o[25] = (float)(p & 7);
  __syncthreads();
  float a = 0.f, bb2 = 0.f;
  #pragma unroll
  for (int c = 0; c < 26; ++c) {
    a   += o[c] * gw1[c * 256 + t];
    bb2 += o[c] * gw1[(26 + c) * 256 + t];
  }
  A[(size_t)bp * 256 + t]  = a;
  Bm[(size_t)bp * 256 + t] = bb2;
  if (p == 0) {
    float cqa = gb1[t];
    #pragma unroll
    for (int c = 0; c < 11; ++c)
      cqa += qst[b * 11 + c] * gw1[(52 + c) * 256 + t];
    Cq[b * 256 + t] = cqa;
  }
}

// ---------------------------------------------------------------------------
// Transpose-convert the 3 W matrices (fp32 [k][n]) -> bf16 [n][k]. Grid 192.
// ---------------------------------------------------------------------------
__global__ __launch_bounds__(256) void wt_convert3(
    const float* __restrict__ W2, const float* __restrict__ W3,
    const float* __restrict__ W4, unsigned short* __restrict__ wt)
{
  const int which = blockIdx.x >> 6;
  const float* W = which == 0 ? W2 : which == 1 ? W3 : W4;
  unsigned short* o = wt + (size_t)which * 65536;
  __shared__ float ts[32][33];
  const int blk = blockIdx.x & 63;
  const int k0 = (blk & 7) * 32, n0 = (blk >> 3) * 32;
  const int t = threadIdx.x;
  const int r = t >> 3, c4 = (t & 7) * 4;
  const float4 v = *(const float4*)(W + (size_t)(k0 + r) * 256 + n0 + c4);
  ts[r][c4 + 0] = v.x; ts[r][c4 + 1] = v.y;
  ts[r][c4 + 2] = v.z; ts[r][c4 + 3] = v.w;
  __syncthreads();
  uint2 ov;
  ov.x = pk2(ts[c4 + 0][r], ts[c4 + 1][r]);
  ov.y = pk2(ts[c4 + 2][r], ts[c4 + 3][r]);
  *(uint2*)(o + (size_t)(n0 + r) * 256 + k0 + c4) = ov;
}

// ---------------------------------------------------------------------------
// Pair MLP via MFMA, register-resident W (NO W LDS round-trip).
// Block: 256 thr / 4 waves, 128 rows x 256 cols; wave tile 64 rows x 128 cols
// (acc[8][4], 32 MFMA per ks from 4 LDS reads + 8 L2 W-loads). h in 64KB
// XOR-swizzled LDS; 2 blocks/CU. ks fully unrolled, af ping-pong af[2][8]
// (ALL indices compile-time -> registers, rule #20). ~6 barriers/block.
// ---------------------------------------------------------------------------
__global__ __launch_bounds__(256, 2) void pair_mfma(
    const float* __restrict__ A, const float* __restrict__ Bm,
    const float* __restrict__ Cq,
    const unsigned short* __restrict__ wtall,
    const float* __restrict__ b2, const float* __restrict__ b3,
    const float* __restrict__ b4,
    float* __restrict__ Gpart)
{
  __shared__ __align__(16) unsigned short hsm[128 * 256];   // 64 KB
  __shared__ float gpart[2][256];                           // 2 KB

  const int tid = threadIdx.x;
  int bid = blockIdx.x;
  bid = (bid & 7) * 256 + (bid >> 3);      // XCD swizzle (2048 = 8*256)
  const int b = bid >> 5, local = bid & 31;
  const int lane = tid & 63, w = tid >> 6;
  const int cg = w & 1, rg = w >> 1;       // col-group (128 cols), row-group (64 rows)
  const int l15 = lane & 15, l4 = lane >> 4;
  char* hbase = (char*)hsm;

  // ---- build h1 = relu(A_i + B_j + Cq) bf16, swizzled. 128 rows = 2 j's.
  {
    const int m = tid >> 1, seg = tid & 1;
    const int jj = local * 2 + (m >> 6), ii = m & 63;
    const float* Ar = A  + (size_t)(b * 64 + ii) * 256 + seg * 128;
    const float* Br = Bm + (size_t)(b * 64 + jj) * 256 + seg * 128;
    const float* Cr = Cq + (size_t)b * 256 + seg * 128;
    #pragma unroll
    for (int it = 0; it < 16; ++it) {
      const float4 a0 = *(const float4*)(Ar + it * 8);
      const float4 a1 = *(const float4*)(Ar + it * 8 + 4);
      const float4 b0 = *(const float4*)(Br + it * 8);
      const float4 b1 = *(const float4*)(Br + it * 8 + 4);
      const float4 c0 = *(const float4*)(Cr + it * 8);
      const float4 c1 = *(const float4*)(Cr + it * 8 + 4);
      uint4 pk;
      pk.x = pk2(fmaxf(a0.x + b0.x + c0.x, 0.f), fmaxf(a0.y + b0.y + c0.y, 0.f));
      pk.y = pk2(fmaxf(a0.z + b0.z + c0.z, 0.f), fmaxf(a0.w + b0.w + c0.w, 0.f));
      pk.z = pk2(fmaxf(a1.x + b1.x + c1.x, 0.f), fmaxf(a1.y + b1.y + c1.y, 0.f));
      pk.w = pk2(fmaxf(a1.z + b1.z + c1.z, 0.f), fmaxf(a1.w + b1.w + c1.w, 0.f));
      const int kb = seg * 256 + it * 16;
      *(uint4*)(hbase + (size_t)m * 512 + (kb ^ ((m & 7) << 4))) = pk;
    }
  }
  __syncthreads();

  const float* bs3[3] = {b2, b3, b4};

  for (int layer = 0; layer < 3; ++layer) {
    // per-lane W base: output-col row n = cg*128 + l15 (+a*16), k off l4*8
    const unsigned short* wrow =
        wtall + (size_t)layer * 65536 + (size_t)(cg * 128 + l15) * 256 + l4 * 8;

    f32x4_t acc[8][4];
    #pragma unroll
    for (int a = 0; a < 8; ++a) {
      const float4 bv = *(const float4*)(bs3[layer] + cg * 128 + a * 16 + l4 * 4);
      #pragma unroll
      for (int t = 0; t < 4; ++t) {
        acc[a][t][0] = bv.x; acc[a][t][1] = bv.y;
        acc[a][t][2] = bv.z; acc[a][t][3] = bv.w;
      }
    }

    bf16x8_t af[2][8];
    #pragma unroll
    for (int a = 0; a < 8; ++a)
      af[0][a] = *(const bf16x8_t*)(wrow + a * 4096);

    #pragma unroll
    for (int ks = 0; ks < 8; ++ks) {
      if (ks < 7) {
        #pragma unroll
        for (int a = 0; a < 8; ++a)
          af[(ks + 1) & 1][a] = *(const bf16x8_t*)(wrow + (ks + 1) * 32 + a * 4096);
      }
      bf16x8_t bf[4];
      #pragma unroll
      for (int t = 0; t < 4; ++t) {
        const int row = rg * 64 + t * 16 + l15;
        const int kb = (ks * 64 + l4 * 16) ^ ((row & 7) << 4);
        bf[t] = *(const bf16x8_t*)(hbase + (size_t)row * 512 + kb);
      }
      #pragma unroll
      for (int a = 0; a < 8; ++a)
        #pragma unroll
        for (int t = 0; t < 4; ++t)
          acc[a][t] = __builtin_amdgcn_mfma_f32_16x16x32_bf16(
              af[ks & 1][a], bf[t], acc[a][t], 0, 0, 0);
    }

    if (layer < 2) {
      __syncthreads();   // all h reads of this layer complete
      #pragma unroll
      for (int a = 0; a < 8; ++a) {
        #pragma unroll
        for (int t = 0; t < 4; ++t) {
          const int row = rg * 64 + t * 16 + l15;
          const int n0 = cg * 128 + a * 16 + l4 * 4;
          uint2 v;
          v.x = pk2(fmaxf(acc[a][t][0], 0.f), fmaxf(acc[a][t][1], 0.f));
          v.y = pk2(fmaxf(acc[a][t][2], 0.f), fmaxf(acc[a][t][3], 0.f));
          *(uint2*)(hbase + (size_t)row * 512 + ((n0 * 2) ^ ((row & 7) << 4))) = v;
        }
      }
      __syncthreads();   // writes visible before next layer reads
    } else {
      #pragma unroll
      for (int a = 0; a < 8; ++a) {
        f32x4_t s;
        s[0] = s[1] = s[2] = s[3] = 0.f;
        #pragma unroll
        for (int t = 0; t < 4; ++t) {
          s[0] += fmaxf(acc[a][t][0], 0.f);
          s[1] += fmaxf(acc[a][t][1], 0.f);
          s[2] += fmaxf(acc[a][t][2], 0.f);
          s[3] += fmaxf(acc[a][t][3], 0.f);
        }
        #pragma unroll
        for (int d = 1; d < 16; d <<= 1) {
          s[0] += __shfl_xor(s[0], d, 64);
          s[1] += __shfl_xor(s[1], d, 64);
          s[2] += __shfl_xor(s[2], d, 64);
          s[3] += __shfl_xor(s[3], d, 64);
        }
        if (l15 == 0)
          *(f32x4_t*)(&gpart[rg][cg * 128 + a * 16 + l4 * 4]) = s;
      }
      __syncthreads();
      Gpart[(size_t)bid * 256 + tid] = gpart[0][tid] + gpart[1][tid];
    }
  }
}

__global__ __launch_bounds__(256) void reduce_g(
    const float* __restrict__ Gpart, float* __restrict__ g)
{
  const int b = blockIdx.x, t = threadIdx.x;
  float s = 0.f;
  for (int j = 0; j < 32; ++j) s += Gpart[(size_t)(b * 32 + j) * 256 + t];
  g[b * 256 + t] = s;
}

// ---------------------------------------------------------------------------
// f-network + softmax. One block per batch element.
// ---------------------------------------------------------------------------
__global__ __launch_bounds__(256) void fnet(
    const float* __restrict__ g,
    const float* __restrict__ fw1, const float* __restrict__ fb1,
    const float* __restrict__ fw2, const float* __restrict__ fb2,
    const float* __restrict__ fw3, const float* __restrict__ fb3,
    float* __restrict__ out)
{
  const int b = blockIdx.x, t = threadIdx.x;
  __shared__ float s0[256], s1[256], lg[10];
  s0[t] = g[b * 256 + t];
  __syncthreads();
  float acc = fb1[t];
  for (int k = 0; k < 256; ++k) acc += s0[k] * fw1[k * 256 + t];
  s1[t] = fmaxf(acc, 0.f);
  __syncthreads();
  acc = fb2[t];
  for (int k = 0; k < 256; ++k) acc += s1[k] * fw2[k * 256 + t];
  s0[t] = fmaxf(acc, 0.f);
  __syncthreads();
  if (t < 10) {
    float a = fb3[t];
    for (int k = 0; k < 256; ++k) a += s0[k] * fw3[k * 10 + t];
    lg[t] = a;
  }
  __syncthreads();
  if (t == 0) {
    float m = lg[0];
    for (int c = 1; c < 10; ++c) m = fmaxf(m, lg[c]);
    float e[10], sum = 0.f;
    for (int c = 0; c < 10; ++c) { e[c] = expf(lg[c] - m); sum += e[c]; }
    const float inv = 1.f / sum;
    for (int c = 0; c < 10; ++c) out[b * 10 + c] = e[c] * inv;
  }
}

// ---------------------------------------------------------------------------
extern "C" void kernel_launch(void* const* d_in, const int* in_sizes, int n_in,
                              void* d_out, int out_size, void* d_ws, size_t ws_size,
                              hipStream_t stream)
{
  const float* img = (const float*)d_in[0];
  const float* qst = (const float*)d_in[1];
  const float* cw[4] = {(const float*)d_in[2],  (const float*)d_in[6],
                        (const float*)d_in[10], (const float*)d_in[14]};
  const float* cb[4] = {(const float*)d_in[3],  (const float*)d_in[7],
                        (const float*)d_in[11], (const float*)d_in[15]};
  const float* bg[4] = {(const float*)d_in[4],  (const float*)d_in[8],
                        (const float*)d_in[12], (const float*)d_in[16]};
  const float* bb[4] = {(const float*)d_in[5],  (const float*)d_in[9],
                        (const float*)d_in[13], (const float*)d_in[17]};
  const float* gw1 = (const float*)d_in[18];
  const float* gb1 = (const float*)d_in[19];
  const float* gw2 = (const float*)d_in[20];
  const float* gb2 = (const float*)d_in[21];
  const float* gw3 = (const float*)d_in[22];
  const float* gb3 = (const float*)d_in[23];
  const float* gw4 = (const float*)d_in[24];
  const float* gb4 = (const float*)d_in[25];
  const float* fw1 = (const float*)d_in[26];
  const float* fb1 = (const float*)d_in[27];
  const float* fw2 = (const float*)d_in[28];
  const float* fb2 = (const float*)d_in[29];
  const float* fw3 = (const float*)d_in[30];
  const float* fb3 = (const float*)d_in[31];
  float* out = (float*)d_out;

  float* ws    = (float*)d_ws;
  float* x1    = ws;                  // 6291456
  float* x2    = x1 + 6291456;        // 1572864
  float* x3    = x2 + 1572864;        // 393216
  float* x4    = x3 + 393216;         // 98304
  float* Abuf  = x4 + 98304;          // 1048576
  float* Bbuf  = Abuf + 1048576;      // 1048576
  float* Cqb   = Bbuf + 1048576;      // 16384
  float* Gpart = Cqb + 16384;         // 524288
  float* gbuf  = Gpart + 524288;      // 16384
  float* stats = gbuf + 16384;        // 192
  unsigned short* wtb = (unsigned short*)(stats + 192);

  hipMemsetAsync(stats, 0, 192 * sizeof(float), stream);

  convk<3, 128, 4, 1, false><<<1024, 256, 0, stream>>>(
      img, cw[0], cb[0], nullptr, nullptr, nullptr, x1, stats + 0);
  convk<24, 64, 8, 1, true><<<256, 256, 0, stream>>>(
      x1, cw[1], cb[1], stats + 0, bg[0], bb[0], x2, stats + 48);
  convk<24, 32, 16, 1, true><<<64, 256, 0, stream>>>(
      x2, cw[2], cb[2], stats + 48, bg[1], bb[1], x3, stats + 96);
  convk<24, 16, 8, 4, true><<<16, 256, 0, stream>>>(
      x3, cw[3], cb[3], stats + 96, bg[2], bb[2], x4, stats + 144);

  build_ab<<<4096, 256, 0, stream>>>(x4, stats + 144, bg[3], bb[3], gw1,
                                     gb1, qst, Abuf, Bbuf, Cqb);
  wt_convert3<<<192, 256, 0, stream>>>(gw2, gw3, gw4, wtb);

  pair_mfma<<<2048, 256, 0, stream>>>(Abuf, Bbuf, Cqb, wtb, gb2, gb3, gb4,
                                      Gpart);
  reduce_g<<<64, 256, 0, stream>>>(Gpart, gbuf);
  fnet<<<64, 256, 0, stream>>>(gbuf, fw1, fb1, fw2, fb2, fw3, fb3, out);
}